// Round 3
// baseline (142.069 us; speedup 1.0000x reference)
//
#include <hip/hip_runtime.h>
#include <math.h>

// Geometry (fixed by setup_inputs):
//   carrier: (B=8, T=32768, 2*FD=258) float32, flat = 67,633,152 floats
//   x[b, s, f, c] -> flat = b*BSTRIDE + s*ROW + 2f + c
#define T_LEN   32768
#define ROW     258
#define BATCH   8
#define BSTRIDE (T_LEN * ROW)        // 8,454,144 floats per batch
#define NFLOAT  (BATCH * BSTRIDE)    // 67,633,152
#define N4      (NFLOAT / 4)         // 16,908,288 float4
#define B4      (BSTRIDE / 4)        // 2,113,536 float4 per batch
#define NBLK    2048
#define NTHR    256
#define P       (NBLK * NTHR)        // 524,288 threads

// Ownership math (grid-stride, stride P):
//   fixup float4 indices are { b*B4 + r : b<8, r<1290 }  (first 5160 floats/batch)
//   i = t + k*P = b*B4 + r  =>  t = 16384*b + r, k = 4*b   (unique solution, k<32)
//   => thread t can fix iff t < 131072 && (t & 16383) < 1290, exactly one float4,
//      during unroll step k = 4*(t>>14). Tail step k=32 is never a fixup position.
__global__ __launch_bounds__(256)
void arith_copy_blend(const float4* __restrict__ x4,
                      float4* __restrict__ o4,
                      const float* __restrict__ blend_p,
                      const int* __restrict__ src_p)
{
    const int t = blockIdx.x * blockDim.x + threadIdx.x;
    const int b = t >> 14;
    const int r = t & 16383;
    const bool canfix = (t < 131072) && (r < 1290);

    #pragma unroll
    for (int g = 0; g < 8; ++g) {
        float4 v[4];
        #pragma unroll
        for (int u = 0; u < 4; ++u)
            v[u] = x4[t + (4 * g + u) * P];

        if (__builtin_expect(canfix && (g == b), 0)) {
            // v[0] is float4 index b*B4 + r -> floats j = 4r..4r+3 of batch b
            const int   src = *src_p;
            const float bl  = 1.0f / (1.0f + expf(-(*blend_p)));  // sigmoid
            const float omb = 1.0f - bl;
            float* e = reinterpret_cast<float*>(&v[0]);
            #pragma unroll
            for (int u = 0; u < 4; ++u) {
                const int j  = 4 * r + u;       // within-batch float offset (< 5160)
                const int s  = j / ROW;         // register index along T
                const int f2 = j - s * ROW;     // 2*freq + comp
                bool  fix = false;
                float sym = 0.0f;
                if (src == 0) {                              // START: regs<20, all freqs
                    fix = (s < 20);
                } else if (src >= 1 && src <= 10) {          // DIGIT
                    if (s >= 2 && s <= 11 && f2 < 2) {
                        fix = true;
                        sym = (s == 2 + (src - 1) % 10 && f2 == 0) ? 1.0f : 0.0f;
                    }
                } else if (src == 11 || src == 12) {         // PLUS / MINUS
                    if (s == 1 && f2 < 2) {
                        fix = true;
                        sym = (f2 == 0) ? ((src == 11) ? 1.0f : -1.0f) : 0.0f;
                    }
                } else if (src == 13) {                      // EQUALS
                    if (((s >= 14 && s <= 16) || s == 1 ||
                         (s >= 2 && s <= 11)) && f2 < 2)
                        fix = true;                          // sym = 0
                }
                if (fix) e[u] = omb * e[u] + bl * sym;
            }
        }

        #pragma unroll
        for (int u = 0; u < 4; ++u)
            o4[t + (4 * g + u) * P] = v[u];
    }

    // Tail: element k=32 exists for the first N4 - 32*P = 131,072 threads.
    if (t < N4 - 32 * P) {
        const int i = t + 32 * P;
        o4[i] = x4[i];
    }
}

extern "C" void kernel_launch(void* const* d_in, const int* in_sizes, int n_in,
                              void* d_out, int out_size, void* d_ws, size_t ws_size,
                              hipStream_t stream) {
    const float4* x4      = (const float4*)d_in[0];  // carrier_freq_flat
    const float*  blend_p = (const float*)d_in[1];   // symbolic_blend (scalar)
    const int*    src_p   = (const int*)d_in[2];     // src_token
    // d_in[3] = tgt_token: only participates in the None-check, unused here.
    float4* o4 = (float4*)d_out;

    arith_copy_blend<<<NBLK, NTHR, 0, stream>>>(x4, o4, blend_p, src_p);
}

// Round 5
// 89.244 us; speedup vs baseline: 1.5919x; 1.5919x over previous
//
#include <hip/hip_runtime.h>
#include <math.h>

// Geometry (fixed by setup_inputs):
//   carrier: (B=8, T=32768, 2*FD=258) float32, flat = 67,633,152 floats
//   x[b, s, f, c] -> flat = b*BSTRIDE + s*ROW + 2f + c
#define T_LEN   32768
#define ROW     258
#define BATCH   8
#define BSTRIDE (T_LEN * ROW)            // 8,454,144 floats per batch
#define NFLOAT  (BATCH * BSTRIDE)        // 67,633,152
#define N4      (NFLOAT / 4)             // 16,908,288 float4
#define FIX_LIM (20 * ROW)               // 5160: fixup positions have (flat % BSTRIDE) < this

// Native clang vector type: __builtin_nontemporal_* requires a real vector,
// not HIP's HIP_vector_type class.
typedef float floatx4 __attribute__((ext_vector_type(4)));

// Round-2 structure (simple grid-stride, 1 load -> 1 store: tied SDMA at 110us),
// plus ONE change: non-temporal stores so the 270MB write stream does not
// write-allocate in L2/L3. The 270MB input then stays mostly L3-resident
// across graph replays (round-3 counters: FETCH was already only 132MB even
// WITH write thrash).
__global__ __launch_bounds__(256)
void arith_copy_blend(const floatx4* __restrict__ x4,
                      floatx4* __restrict__ o4,
                      const float* __restrict__ blend_p,
                      const int* __restrict__ src_p)
{
    const int stride = gridDim.x * blockDim.x;
    for (int i = blockIdx.x * blockDim.x + threadIdx.x; i < N4; i += stride) {
        floatx4 v = x4[i];
        const unsigned flat = (unsigned)i << 2;
        const unsigned b    = flat / (unsigned)BSTRIDE;   // magic-mul (const divisor)
        const int      rem  = (int)(flat - b * (unsigned)BSTRIDE);

        if (__builtin_expect(rem < FIX_LIM, 0)) {
            const int   src = *src_p;
            const float bl  = 1.0f / (1.0f + expf(-(*blend_p)));   // sigmoid
            const float omb = 1.0f - bl;
            #pragma unroll
            for (int k = 0; k < 4; ++k) {
                const int j  = rem + k;        // within-batch flat offset
                const int s  = j / ROW;        // register index along T
                const int f2 = j - s * ROW;    // 2*freq + comp
                bool  fix = false;
                float sym = 0.0f;
                if (src == 0) {                               // START: regs<20, all freqs
                    fix = (s < 20);
                } else if (src >= 1 && src <= 10) {           // DIGIT
                    if (s >= 2 && s <= 11 && f2 < 2) {
                        fix = true;
                        sym = (s == 2 + (src - 1) % 10 && f2 == 0) ? 1.0f : 0.0f;
                    }
                } else if (src == 11 || src == 12) {          // PLUS / MINUS
                    if (s == 1 && f2 < 2) {
                        fix = true;
                        sym = (f2 == 0) ? ((src == 11) ? 1.0f : -1.0f) : 0.0f;
                    }
                } else if (src == 13) {                       // EQUALS
                    if (((s >= 14 && s <= 16) || s == 1 ||
                         (s >= 2 && s <= 11)) && f2 < 2)
                        fix = true;                           // sym = 0
                }
                if (fix) v[k] = omb * v[k] + bl * sym;
            }
        }
        __builtin_nontemporal_store(v, &o4[i]);
    }
}

extern "C" void kernel_launch(void* const* d_in, const int* in_sizes, int n_in,
                              void* d_out, int out_size, void* d_ws, size_t ws_size,
                              hipStream_t stream) {
    const floatx4* x4      = (const floatx4*)d_in[0];  // carrier_freq_flat
    const float*   blend_p = (const float*)d_in[1];    // symbolic_blend (scalar)
    const int*     src_p   = (const int*)d_in[2];      // src_token
    // d_in[3] = tgt_token: only participates in the None-check, unused here.
    floatx4* o4 = (floatx4*)d_out;

    arith_copy_blend<<<2048, 256, 0, stream>>>(x4, o4, blend_p, src_p);
}